// Round 5
// baseline (29.485 us; speedup 1.0000x reference)
//
#include <hip/hip_runtime.h>

// Problem constants (match reference)
#define BATCH    128
#define NEV      16
#define NS       32768
#define STEP     256
#define TILE     1024                 // floats per tile (256 threads x float4)
#define NTILES   (NS / TILE)          // 32 tiles per batch
#define NPAIR    (NTILES / 2)         // 16 tile-pairs per batch

// Native clang vector type: __builtin_nontemporal_load/store require a
// vector-of-scalar type, not HIP's struct float4.
typedef float f32x4 __attribute__((ext_vector_type(4)));

// R2 structure (best measured): each block computes tiles j and 31-j.
// R4 delta: nontemporal load/store hints — x and out are pure streaming
// (zero reuse), so bypass L2 allocation.
__global__ __launch_bounds__(256)
void summarizer_gather_kernel(const float* __restrict__ x,
                              const int* __restrict__ idx,
                              float* __restrict__ out)
{
    const int p = blockIdx.x % NPAIR;        // tile pair 0..15
    const int b = blockIdx.x / NPAIR;        // batch

    const int tA = p * TILE + (int)threadIdx.x * 4;                  // early tile
    const int tB = (NTILES - 1 - p) * TILE + (int)threadIdx.x * 4;   // late tile

    const float* xb = x + (size_t)b * NEV * NS;
    const int*   ib = idx + b * NEV;         // block-uniform address -> s_load

    f32x4 accA = (f32x4)(0.f);
    f32x4 accB = (f32x4)(0.f);

    // Starts are multiples of 256; each wave's 64 lanes x float4 cover exactly
    // 256 contiguous 256-aligned samples -> (t >= s) is wave-uniform: skipped
    // loads cost zero bandwidth, zero divergence.
    #pragma unroll
    for (int i = 0; i < NEV; ++i) {
        const int s = ib[i] * STEP;
        const float* xe = xb + (size_t)i * NS - s;
        if (tA >= s) {
            accA += __builtin_nontemporal_load(
                reinterpret_cast<const f32x4*>(xe + tA));
        }
        if (tB >= s) {
            accB += __builtin_nontemporal_load(
                reinterpret_cast<const f32x4*>(xe + tB));
        }
    }

    float* ob = out + (size_t)b * NS;
    __builtin_nontemporal_store(accA, reinterpret_cast<f32x4*>(ob + tA));
    __builtin_nontemporal_store(accB, reinterpret_cast<f32x4*>(ob + tB));
}

extern "C" void kernel_launch(void* const* d_in, const int* in_sizes, int n_in,
                              void* d_out, int out_size, void* d_ws, size_t ws_size,
                              hipStream_t stream)
{
    const float* x   = (const float*)d_in[0];   // [128, 16, 32768] f32
    const int*   idx = (const int*)d_in[1];     // [128, 16] int32
    float*       out = (float*)d_out;           // [128, 1, 32768] f32

    const int grid = BATCH * NPAIR;             // 2048 blocks = 8/CU, 32 waves/CU
    summarizer_gather_kernel<<<grid, 256, 0, stream>>>(x, idx, out);
}

// Round 6
// 27.779 us; speedup vs baseline: 1.0614x; 1.0614x over previous
//
#include <hip/hip_runtime.h>

// Problem constants (match reference)
#define BATCH    128
#define NEV      16
#define NS       32768
#define STEP     256
#define TILE     1024                 // floats per tile (256 threads x float4)
#define NTILES   (NS / TILE)          // 32 tiles per batch
#define NPAIR    (NTILES / 2)         // 16 tile-pairs per batch

// Best measured configuration (R2, 27.8 us = 5.47 TB/s effective on the
// compulsory 152 MB). Scatter inverted to gather: out[b,t] = sum_i
// x[b,i,t-s_i] for t >= s_i. Each block computes tiles j and 31-j
// (complementary load volume); 2048 blocks = 8/CU = full 32-wave residency.
// Measured dead ends: per-block work balancing (R3, null), nontemporal
// hints (R5, -6%), 512-thread blocks (R3, null).
__global__ __launch_bounds__(256)
void summarizer_gather_kernel(const float* __restrict__ x,
                              const int* __restrict__ idx,
                              float* __restrict__ out)
{
    const int p = blockIdx.x % NPAIR;        // tile pair 0..15
    const int b = blockIdx.x / NPAIR;        // batch

    const int tA = p * TILE + (int)threadIdx.x * 4;                  // early tile
    const int tB = (NTILES - 1 - p) * TILE + (int)threadIdx.x * 4;   // late tile

    const float* xb = x + (size_t)b * NEV * NS;
    const int*   ib = idx + b * NEV;         // block-uniform address -> s_load

    float4 accA = make_float4(0.f, 0.f, 0.f, 0.f);
    float4 accB = make_float4(0.f, 0.f, 0.f, 0.f);

    // Starts are multiples of 256; each wave's 64 lanes x float4 cover exactly
    // 256 contiguous 256-aligned samples -> (t >= s) is wave-uniform: skipped
    // loads cost zero bandwidth, zero divergence.
    #pragma unroll
    for (int i = 0; i < NEV; ++i) {
        const int s = ib[i] * STEP;
        const float* xe = xb + (size_t)i * NS - s;
        if (tA >= s) {
            const float4 v = *reinterpret_cast<const float4*>(xe + tA);
            accA.x += v.x; accA.y += v.y; accA.z += v.z; accA.w += v.w;
        }
        if (tB >= s) {
            const float4 v = *reinterpret_cast<const float4*>(xe + tB);
            accB.x += v.x; accB.y += v.y; accB.z += v.z; accB.w += v.w;
        }
    }

    float* ob = out + (size_t)b * NS;
    *reinterpret_cast<float4*>(ob + tA) = accA;
    *reinterpret_cast<float4*>(ob + tB) = accB;
}

extern "C" void kernel_launch(void* const* d_in, const int* in_sizes, int n_in,
                              void* d_out, int out_size, void* d_ws, size_t ws_size,
                              hipStream_t stream)
{
    const float* x   = (const float*)d_in[0];   // [128, 16, 32768] f32
    const int*   idx = (const int*)d_in[1];     // [128, 16] int32
    float*       out = (float*)d_out;           // [128, 1, 32768] f32

    const int grid = BATCH * NPAIR;             // 2048 blocks = 8/CU, 32 waves/CU
    summarizer_gather_kernel<<<grid, 256, 0, stream>>>(x, idx, out);
}